// Round 1
// baseline (101.701 us; speedup 1.0000x reference)
//
#include <hip/hip_runtime.h>
#include <hip/hip_bf16.h>

// ---------------------------------------------------------------------------
// LogicLayer inference:
//   pA = softmax(WA, axis=1); pB = softmax(WB, axis=1); pT = softmax(TW, axis=0)
//   a = pA @ prev; b = pB @ prev
//   out = sum_g pT[g,s] * gate_g(a,b)
// Every gate is bilinear in (a,b):  gate = c0 + cA*a + cB*b + cAB*a*b
//   => out[s,n] = w0[s] + wA[s]*a + wB[s]*b + wAB[s]*a*b
// So: 2 GEMMs (shared B operand) in bf16 MFMA + 4-coefficient epilogue.
// ---------------------------------------------------------------------------

typedef __attribute__((ext_vector_type(8))) short bf16x8;   // 8 bf16 = 4 VGPR
typedef __attribute__((ext_vector_type(4))) float f32x4;

__device__ __forceinline__ void gload_lds16(const void* g, void* l) {
    // async global->LDS, 16B/lane; LDS dest = wave-uniform base + lane*16
    __builtin_amdgcn_global_load_lds(
        (const __attribute__((address_space(1))) void*)g,
        (__attribute__((address_space(3))) void*)l, 16, 0, 0);
}

// ---------------- kernel 1: row softmax of WA/WB -> bf16 -------------------
// cols == 1024 assumed (256 threads * 4 elems)
__global__ __launch_bounds__(256) void softmax_rows_bf16(
    const float* __restrict__ WA, const float* __restrict__ WB,
    __hip_bfloat16* __restrict__ PA, __hip_bfloat16* __restrict__ PB,
    int rows, int cols)
{
    const int b = blockIdx.x;
    const float* W;
    __hip_bfloat16* P;
    if (b < rows) { W = WA + (size_t)b * cols;          P = PA + (size_t)b * cols; }
    else          { W = WB + (size_t)(b - rows) * cols; P = PB + (size_t)(b - rows) * cols; }

    const int t = threadIdx.x;
    const int wave = t >> 6, lane = t & 63;

    float4 v = *(const float4*)&W[t * 4];
    float mx = fmaxf(fmaxf(v.x, v.y), fmaxf(v.z, v.w));
    #pragma unroll
    for (int off = 32; off; off >>= 1) mx = fmaxf(mx, __shfl_xor(mx, off));

    __shared__ float redmax[4];
    __shared__ float redsum[4];
    if (lane == 0) redmax[wave] = mx;
    __syncthreads();
    mx = fmaxf(fmaxf(redmax[0], redmax[1]), fmaxf(redmax[2], redmax[3]));

    float e0 = __expf(v.x - mx), e1 = __expf(v.y - mx);
    float e2 = __expf(v.z - mx), e3 = __expf(v.w - mx);
    float s = e0 + e1 + e2 + e3;
    #pragma unroll
    for (int off = 32; off; off >>= 1) s += __shfl_xor(s, off);
    if (lane == 0) redsum[wave] = s;
    __syncthreads();
    s = redsum[0] + redsum[1] + redsum[2] + redsum[3];

    const float inv = 1.0f / s;
    __align__(8) __hip_bfloat16 o[4];
    o[0] = __float2bfloat16(e0 * inv);
    o[1] = __float2bfloat16(e1 * inv);
    o[2] = __float2bfloat16(e2 * inv);
    o[3] = __float2bfloat16(e3 * inv);
    *(uint2*)&P[t * 4] = *(const uint2*)o;
}

// ---------------- kernel 2: table softmax -> bilinear coeffs ----------------
__global__ void table_coef(const float* __restrict__ TW, float4* __restrict__ coef, int size)
{
    const int s = blockIdx.x * blockDim.x + threadIdx.x;
    if (s >= size) return;
    float p[16];
    float mx = -1e30f;
    #pragma unroll
    for (int g = 0; g < 16; ++g) { p[g] = TW[g * size + s]; mx = fmaxf(mx, p[g]); }
    float sum = 0.f;
    #pragma unroll
    for (int g = 0; g < 16; ++g) { p[g] = __expf(p[g] - mx); sum += p[g]; }
    const float inv = 1.0f / sum;
    #pragma unroll
    for (int g = 0; g < 16; ++g) p[g] *= inv;

    // gate_g(a,b) = c0 + cA*a + cB*b + cAB*a*b, summed with weights p[g]:
    float w0  = p[8] + p[9] + p[10] + p[11] + p[12] + p[13] + p[14] + p[15];
    float wA  = p[2] + p[3] + p[6] + p[7] - p[8] - p[9] - p[12] - p[13];
    float wB  = p[4] + p[5] + p[6] + p[7] - p[8] - p[9] - p[10] - p[11];
    float wAB = p[1] - p[2] - p[4] - 2.f * p[6] - p[7]
              + p[8] + 2.f * p[9] + p[11] + p[13] - p[14];
    coef[s] = make_float4(w0, wA, wB, wAB);
}

// ---------------- kernel 3: prev (K x N f32) -> prevT (N x K bf16) ----------
__global__ __launch_bounds__(256) void transpose_bf16(
    const float* __restrict__ prev, __hip_bfloat16* __restrict__ prevT,
    int K, int N)
{
    __shared__ float ls[64][65];           // +1 pad: conflict-free-ish
    const int k0 = blockIdx.y * 64, n0 = blockIdx.x * 64;
    const int t = threadIdx.x;

    {
        const int kr = t >> 4, nc = (t & 15) * 4;
        #pragma unroll
        for (int i = 0; i < 4; ++i) {
            const int k = i * 16 + kr;
            float4 v = *(const float4*)&prev[(size_t)(k0 + k) * N + n0 + nc];
            ls[k][nc + 0] = v.x; ls[k][nc + 1] = v.y;
            ls[k][nc + 2] = v.z; ls[k][nc + 3] = v.w;
        }
    }
    __syncthreads();
    {
        const int n = t >> 2, kc = (t & 3) * 16;
        __align__(16) __hip_bfloat16 tmp[16];
        #pragma unroll
        for (int j = 0; j < 16; ++j) tmp[j] = __float2bfloat16(ls[kc + j][n]);
        __hip_bfloat16* dst = &prevT[(size_t)(n0 + n) * K + k0 + kc];
        *(uint4*)(dst + 0) = *(const uint4*)&tmp[0];
        *(uint4*)(dst + 8) = *(const uint4*)&tmp[8];
    }
}

// ---------------- kernel 4: dual GEMM + bilinear epilogue -------------------
// C_a = pA @ prev, C_b = pB @ prev  (shared prevT operand tile)
// out = w0 + wA*a + wB*b + wAB*a*b
// m97 structure: 128x128 tile, BK=32, 4 waves (2x2), global_load_lds w=16.
__global__ __launch_bounds__(256, 2) void dual_gemm(
    const __hip_bfloat16* __restrict__ pA,
    const __hip_bfloat16* __restrict__ pB,
    const __hip_bfloat16* __restrict__ prevT,
    const float4* __restrict__ coef,
    float* __restrict__ out,
    int M, int N, int K)
{
    __shared__ __hip_bfloat16 sAa[128][32];  // 8KB each
    __shared__ __hip_bfloat16 sAb[128][32];
    __shared__ __hip_bfloat16 sB [128][32];

    const int t = threadIdx.x;
    const int wave = t >> 6, lane = t & 63;
    const int wr = wave >> 1, wc = wave & 1;       // 2x2 wave grid, 64x64 each
    const int m0 = blockIdx.y * 128, n0 = blockIdx.x * 128;

    const int srow  = lane >> 2;                    // staging: row within chunk
    const int scol8 = (lane & 3) * 8;               // staging: k offset

    const int fr = lane & 15;                       // fragment row/col index
    const int kg = lane >> 4;                       // fragment k-group (*8)

    f32x4 acc_a[4][4] = {};
    f32x4 acc_b[4][4] = {};

    for (int k0 = 0; k0 < K; k0 += 32) {
        __syncthreads();
        #pragma unroll
        for (int i = 0; i < 2; ++i) {
            const int chunk = wave * 2 + i;          // 8 chunks of 16 rows
            const int row = chunk * 16 + srow;
            gload_lds16(&pA   [(size_t)(m0 + row) * K + k0 + scol8], &sAa[chunk * 16][0]);
            gload_lds16(&pB   [(size_t)(m0 + row) * K + k0 + scol8], &sAb[chunk * 16][0]);
            gload_lds16(&prevT[(size_t)(n0 + row) * K + k0 + scol8], &sB [chunk * 16][0]);
        }
        __syncthreads();   // compiler drains vmcnt before barrier

        bf16x8 fa[4], fb[4], fv[4];
        #pragma unroll
        for (int i = 0; i < 4; ++i) {
            fa[i] = *(const bf16x8*)&sAa[wr * 64 + i * 16 + fr][kg * 8];
            fb[i] = *(const bf16x8*)&sAb[wr * 64 + i * 16 + fr][kg * 8];
            fv[i] = *(const bf16x8*)&sB [wc * 64 + i * 16 + fr][kg * 8];
        }
        #pragma unroll
        for (int i = 0; i < 4; ++i) {
            #pragma unroll
            for (int j = 0; j < 4; ++j) {
                acc_a[i][j] = __builtin_amdgcn_mfma_f32_16x16x32_bf16(fa[i], fv[j], acc_a[i][j], 0, 0, 0);
                acc_b[i][j] = __builtin_amdgcn_mfma_f32_16x16x32_bf16(fb[i], fv[j], acc_b[i][j], 0, 0, 0);
            }
        }
    }

    // epilogue: C/D layout col = lane&15, row = (lane>>4)*4 + reg   [m89/m91]
    #pragma unroll
    for (int i = 0; i < 4; ++i) {
        #pragma unroll
        for (int r = 0; r < 4; ++r) {
            const int m = m0 + wr * 64 + i * 16 + kg * 4 + r;
            const float4 c = coef[m];
            #pragma unroll
            for (int j = 0; j < 4; ++j) {
                const int n = n0 + wc * 64 + j * 16 + fr;
                const float a = acc_a[i][j][r];
                const float b = acc_b[i][j][r];
                out[(size_t)m * N + n] = c.x + c.y * a + c.z * b + c.w * (a * b);
            }
        }
    }
}

// ---------------------------------------------------------------------------
extern "C" void kernel_launch(void* const* d_in, const int* in_sizes, int n_in,
                              void* d_out, int out_size, void* d_ws, size_t ws_size,
                              hipStream_t stream)
{
    const float* prev = (const float*)d_in[0];   // (prev_size, batch)
    const float* WA   = (const float*)d_in[1];   // (size, prev_size)
    const float* WB   = (const float*)d_in[2];   // (size, prev_size)
    const float* TW   = (const float*)d_in[3];   // (16, size)
    float* out = (float*)d_out;                  // (size, batch)

    const int size      = in_sizes[3] / 16;          // 1024
    const int prev_size = in_sizes[1] / size;        // 1024
    const int batch     = in_sizes[0] / prev_size;   // 16384

    // workspace layout (all bf16/f32, 16B-aligned):
    char* ws = (char*)d_ws;
    __hip_bfloat16* prevT = (__hip_bfloat16*)ws;                       // batch*prev_size*2 = 32MB
    size_t off = (size_t)batch * prev_size * sizeof(__hip_bfloat16);
    __hip_bfloat16* pA = (__hip_bfloat16*)(ws + off);
    off += (size_t)size * prev_size * sizeof(__hip_bfloat16);
    __hip_bfloat16* pB = (__hip_bfloat16*)(ws + off);
    off += (size_t)size * prev_size * sizeof(__hip_bfloat16);
    float4* coef = (float4*)(ws + off);

    softmax_rows_bf16<<<dim3(2 * size), dim3(256), 0, stream>>>(
        WA, WB, pA, pB, size, prev_size);
    table_coef<<<dim3((size + 255) / 256), dim3(256), 0, stream>>>(TW, coef, size);
    transpose_bf16<<<dim3(batch / 64, prev_size / 64), dim3(256), 0, stream>>>(
        prev, prevT, prev_size, batch);
    dual_gemm<<<dim3(batch / 128, size / 128), dim3(256), 0, stream>>>(
        pA, pB, prevT, coef, out, size, batch, prev_size);
}

// Round 2
// 95.439 us; speedup vs baseline: 1.0656x; 1.0656x over previous
//
#include <hip/hip_runtime.h>
#include <hip/hip_bf16.h>

// ---------------------------------------------------------------------------
// LogicLayer inference (sizes fixed by harness: size=1024, prev=1024, batch=16384)
//   out[s,n] = w0[s] + wA[s]*a + wB[s]*b + wAB[s]*a*b,  a = pA@prev, b = pB@prev
// Round 2: dual-GEMM rewritten as 8-phase-style pipelined 256x256 tile:
//   - stacked A-tile: rows 0-127 = pA panel, 128-255 = pB panel
//   - BK=32, 4 LDS buffers (128KB), 3-tile prefetch lead, counted vmcnt(8)
//   - chunk-XOR LDS swizzle (both sides: pre-swizzled global src + swizzled read)
//   - raw s_barrier + lgkmcnt(0) + sched_barrier(0) + setprio around MFMA
//   - epilogue: b-waves exchange acc via LDS, a-waves fuse bilinear coeffs
// ---------------------------------------------------------------------------

typedef __attribute__((ext_vector_type(8))) short bf16x8;
typedef __attribute__((ext_vector_type(4))) float f32x4;

__device__ __forceinline__ void gload_lds16(const void* g, void* l) {
    __builtin_amdgcn_global_load_lds(
        (const __attribute__((address_space(1))) void*)g,
        (__attribute__((address_space(3))) void*)l, 16, 0, 0);
}

// ---------------- kernel 1: row softmax of WA/WB -> bf16 -------------------
__global__ __launch_bounds__(256) void softmax_rows_bf16(
    const float* __restrict__ WA, const float* __restrict__ WB,
    __hip_bfloat16* __restrict__ PA, __hip_bfloat16* __restrict__ PB,
    int rows, int cols)
{
    const int b = blockIdx.x;
    const float* W;
    __hip_bfloat16* P;
    if (b < rows) { W = WA + (size_t)b * cols;          P = PA + (size_t)b * cols; }
    else          { W = WB + (size_t)(b - rows) * cols; P = PB + (size_t)(b - rows) * cols; }

    const int t = threadIdx.x;
    const int wave = t >> 6, lane = t & 63;

    float4 v = *(const float4*)&W[t * 4];
    float mx = fmaxf(fmaxf(v.x, v.y), fmaxf(v.z, v.w));
    #pragma unroll
    for (int off = 32; off; off >>= 1) mx = fmaxf(mx, __shfl_xor(mx, off));

    __shared__ float redmax[4];
    __shared__ float redsum[4];
    if (lane == 0) redmax[wave] = mx;
    __syncthreads();
    mx = fmaxf(fmaxf(redmax[0], redmax[1]), fmaxf(redmax[2], redmax[3]));

    float e0 = __expf(v.x - mx), e1 = __expf(v.y - mx);
    float e2 = __expf(v.z - mx), e3 = __expf(v.w - mx);
    float s = e0 + e1 + e2 + e3;
    #pragma unroll
    for (int off = 32; off; off >>= 1) s += __shfl_xor(s, off);
    if (lane == 0) redsum[wave] = s;
    __syncthreads();
    s = redsum[0] + redsum[1] + redsum[2] + redsum[3];

    const float inv = 1.0f / s;
    __align__(8) __hip_bfloat16 o[4];
    o[0] = __float2bfloat16(e0 * inv);
    o[1] = __float2bfloat16(e1 * inv);
    o[2] = __float2bfloat16(e2 * inv);
    o[3] = __float2bfloat16(e3 * inv);
    *(uint2*)&P[t * 4] = *(const uint2*)o;
}

// ---------------- kernel 2: table softmax -> bilinear coeffs ----------------
__global__ void table_coef(const float* __restrict__ TW, float4* __restrict__ coef, int size)
{
    const int s = blockIdx.x * blockDim.x + threadIdx.x;
    if (s >= size) return;
    float p[16];
    float mx = -1e30f;
    #pragma unroll
    for (int g = 0; g < 16; ++g) { p[g] = TW[g * size + s]; mx = fmaxf(mx, p[g]); }
    float sum = 0.f;
    #pragma unroll
    for (int g = 0; g < 16; ++g) { p[g] = __expf(p[g] - mx); sum += p[g]; }
    const float inv = 1.0f / sum;
    #pragma unroll
    for (int g = 0; g < 16; ++g) p[g] *= inv;

    float w0  = p[8] + p[9] + p[10] + p[11] + p[12] + p[13] + p[14] + p[15];
    float wA  = p[2] + p[3] + p[6] + p[7] - p[8] - p[9] - p[12] - p[13];
    float wB  = p[4] + p[5] + p[6] + p[7] - p[8] - p[9] - p[10] - p[11];
    float wAB = p[1] - p[2] - p[4] - 2.f * p[6] - p[7]
              + p[8] + 2.f * p[9] + p[11] + p[13] - p[14];
    coef[s] = make_float4(w0, wA, wB, wAB);
}

// ---------------- kernel 3: prev (K x N f32) -> prevT (N x K bf16) ----------
__global__ __launch_bounds__(256) void transpose_bf16(
    const float* __restrict__ prev, __hip_bfloat16* __restrict__ prevT,
    int K, int N)
{
    __shared__ float ls[64][65];
    const int k0 = blockIdx.y * 64, n0 = blockIdx.x * 64;
    const int t = threadIdx.x;

    {
        const int kr = t >> 4, nc = (t & 15) * 4;
        #pragma unroll
        for (int i = 0; i < 4; ++i) {
            const int k = i * 16 + kr;
            float4 v = *(const float4*)&prev[(size_t)(k0 + k) * N + n0 + nc];
            ls[k][nc + 0] = v.x; ls[k][nc + 1] = v.y;
            ls[k][nc + 2] = v.z; ls[k][nc + 3] = v.w;
        }
    }
    __syncthreads();
    {
        const int n = t >> 2, kc = (t & 3) * 16;
        __align__(16) __hip_bfloat16 tmp[16];
        #pragma unroll
        for (int j = 0; j < 16; ++j) tmp[j] = __float2bfloat16(ls[kc + j][n]);
        __hip_bfloat16* dst = &prevT[(size_t)(n0 + n) * K + k0 + kc];
        *(uint4*)(dst + 0) = *(const uint4*)&tmp[0];
        *(uint4*)(dst + 8) = *(const uint4*)&tmp[8];
    }
}

// ---------------- kernel 4: 8-phase-style pipelined dual GEMM ---------------
// Block tile: 256 stacked A-rows (128 pA + 128 pB) x 256 cols, BK=32.
// 8 waves in 2(M-half: a/b) x 4(N) grid, each wave: 128x64 output (8x4 frags).
// LDS: 4 buffers x (A 16KB + B 16KB) = 128KB, 3-tile prefetch lead.
// Sizes hardcoded: K=1024 (32 tiles), N=16384.
constexpr int BK_   = 32;
constexpr int NTIL  = 32;        // 1024 / 32
constexpr int BUF   = 32768;     // bytes per buffer
constexpr int BOFF_ = 16384;     // B offset within buffer
constexpr int Kd    = 1024;
constexpr int Nd    = 16384;

__global__ __launch_bounds__(512, 2) void dual_gemm8(
    const __hip_bfloat16* __restrict__ pA,
    const __hip_bfloat16* __restrict__ pB,
    const __hip_bfloat16* __restrict__ prevT,
    const float4* __restrict__ coef,
    float* __restrict__ out)
{
    __shared__ __align__(16) char smem[131072];

    const int t = threadIdx.x;
    const int wave = t >> 6, lane = t & 63;
    const int wr = wave >> 2, wc = wave & 3;      // wr: 0=a-half, 1=b-half
    const int m0 = blockIdx.y * 128;
    const int n0 = blockIdx.x * 256;

    // --- fragment-read addressing (byte offsets, buffer-relative) ---
    const int fr  = lane & 15;
    const int kg  = lane >> 4;                              // k-chunk 0..3
    const int csw = ((kg ^ ((fr >> 1) & 3)) << 4);          // swizzled chunk
    const int aoff = (wr * 128 + fr) * 64 + csw;            // + i*1024
    const int boff = BOFF_ + (wc * 64 + fr) * 64 + csw;     // + j*1024

    // --- staging addressing (per-lane global src, pre-swizzled k) ---
    const int srow = lane >> 2;                             // row in 16-row grp
    const int sksw = ((lane & 3) ^ ((lane >> 3) & 3)) * 8;  // swizzled k elems
    const int arow = 16 * wave + srow;                      // 0..127 per half
    const __hip_bfloat16* gA0 = pA    + (size_t)(m0 + arow) * Kd + sksw;
    const __hip_bfloat16* gA1 = pB    + (size_t)(m0 + arow) * Kd + sksw;
    const __hip_bfloat16* gB0 = prevT + (size_t)(n0 + arow) * Kd + sksw;
    const __hip_bfloat16* gB1 = prevT + (size_t)(n0 + 128 + arow) * Kd + sksw;

    // wave-uniform LDS staging bases: issue q -> rows 16*(wave+8q)
    auto STAGE_A = [&](int T) {
        char* base = smem + (T & 3) * BUF + wave * 1024;
        const int kT = T * BK_;
        gload_lds16(gA0 + kT, base);
        gload_lds16(gA1 + kT, base + 8192);
    };
    auto STAGE_B = [&](int T) {
        char* base = smem + (T & 3) * BUF + BOFF_ + wave * 1024;
        const int kT = T * BK_;
        gload_lds16(gB0 + kT, base);
        gload_lds16(gB1 + kT, base + 8192);
    };

    f32x4 acc[8][4] = {};
    bf16x8 af[8], bf_[4];

#define PH_MFMA(I0)                                                         \
    asm volatile("s_waitcnt lgkmcnt(0)" ::: "memory");                      \
    __builtin_amdgcn_sched_barrier(0);                                      \
    __builtin_amdgcn_s_setprio(1);                                          \
    _Pragma("unroll")                                                       \
    for (int i = (I0); i < (I0) + 4; ++i) {                                 \
        _Pragma("unroll")                                                   \
        for (int j = 0; j < 4; ++j)                                         \
            acc[i][j] = __builtin_amdgcn_mfma_f32_16x16x32_bf16(            \
                af[i], bf_[j], acc[i][j], 0, 0, 0);                         \
    }                                                                       \
    __builtin_amdgcn_s_setprio(0);

#define DO_TILE(TT, STG, VMSTR)                                             \
  {                                                                         \
    const char* buf = smem + ((TT) & 3) * BUF;                              \
    _Pragma("unroll")                                                       \
    for (int i = 0; i < 4; ++i)                                             \
        af[i] = *(const bf16x8*)(buf + aoff + i * 1024);                    \
    _Pragma("unroll")                                                       \
    for (int j = 0; j < 4; ++j)                                             \
        bf_[j] = *(const bf16x8*)(buf + boff + j * 1024);                   \
    if (STG) STAGE_A((TT) + 3);                                             \
    __builtin_amdgcn_s_barrier();                                           \
    PH_MFMA(0)                                                              \
    __builtin_amdgcn_s_barrier();                                           \
    _Pragma("unroll")                                                       \
    for (int i = 4; i < 8; ++i)                                             \
        af[i] = *(const bf16x8*)(buf + aoff + i * 1024);                    \
    if (STG) STAGE_B((TT) + 3);                                             \
    asm volatile("s_waitcnt " VMSTR ::: "memory");                          \
    __builtin_amdgcn_s_barrier();                                           \
    PH_MFMA(4)                                                              \
    __builtin_amdgcn_s_barrier();                                           \
  }

    // prologue: stage tiles 0,1,2; wait tile 0 (8 newer loads outstanding ok)
    STAGE_A(0); STAGE_B(0);
    STAGE_A(1); STAGE_B(1);
    STAGE_A(2); STAGE_B(2);
    asm volatile("s_waitcnt vmcnt(8)" ::: "memory");
    __builtin_amdgcn_s_barrier();

    // steady state: boundary vmcnt(8) guarantees next tile staged
    for (int tt = 0; tt < NTIL - 3; ++tt) {
        DO_TILE(tt, 1, "vmcnt(8)")
    }
    // tail: drain 8 -> 4 -> 0
    DO_TILE(NTIL - 3, 0, "vmcnt(4)")
    DO_TILE(NTIL - 2, 0, "vmcnt(0)")
    DO_TILE(NTIL - 1, 0, "vmcnt(0)")

#undef DO_TILE
#undef PH_MFMA

    // ---- epilogue: exchange b-acc via LDS, fuse bilinear coefficients ----
    __syncthreads();
    if (wr == 1) {
        #pragma unroll
        for (int i = 0; i < 8; ++i) {
            #pragma unroll
            for (int j = 0; j < 4; ++j) {
                const int off = ((((wc * 8 + i) * 4 + j) * 64) + lane) * 16;
                *(f32x4*)(smem + off) = acc[i][j];
            }
        }
    }
    __syncthreads();
    if (wr == 0) {
        const int hi = lane >> 4;
        #pragma unroll
        for (int i = 0; i < 8; ++i) {
            float4 cc[4];
            #pragma unroll
            for (int r = 0; r < 4; ++r) cc[r] = coef[m0 + i * 16 + hi * 4 + r];
            #pragma unroll
            for (int j = 0; j < 4; ++j) {
                const f32x4 bb = *(const f32x4*)(smem + ((((wc * 8 + i) * 4 + j) * 64) + lane) * 16);
                const int n = n0 + wc * 64 + j * 16 + fr;
                #pragma unroll
                for (int r = 0; r < 4; ++r) {
                    const int m = m0 + i * 16 + hi * 4 + r;
                    const float a = acc[i][j][r];
                    out[(size_t)m * Nd + n] = cc[r].x + cc[r].y * a + cc[r].z * bb[r]
                                            + cc[r].w * (a * bb[r]);
                }
            }
        }
    }
}

// ---------------------------------------------------------------------------
extern "C" void kernel_launch(void* const* d_in, const int* in_sizes, int n_in,
                              void* d_out, int out_size, void* d_ws, size_t ws_size,
                              hipStream_t stream)
{
    const float* prev = (const float*)d_in[0];   // (prev_size, batch)
    const float* WA   = (const float*)d_in[1];   // (size, prev_size)
    const float* WB   = (const float*)d_in[2];   // (size, prev_size)
    const float* TW   = (const float*)d_in[3];   // (16, size)
    float* out = (float*)d_out;                  // (size, batch)

    const int size      = in_sizes[3] / 16;          // 1024
    const int prev_size = in_sizes[1] / size;        // 1024
    const int batch     = in_sizes[0] / prev_size;   // 16384

    char* ws = (char*)d_ws;
    __hip_bfloat16* prevT = (__hip_bfloat16*)ws;     // 32MB
    size_t off = (size_t)batch * prev_size * sizeof(__hip_bfloat16);
    __hip_bfloat16* pA = (__hip_bfloat16*)(ws + off);
    off += (size_t)size * prev_size * sizeof(__hip_bfloat16);
    __hip_bfloat16* pB = (__hip_bfloat16*)(ws + off);
    off += (size_t)size * prev_size * sizeof(__hip_bfloat16);
    float4* coef = (float4*)(ws + off);

    softmax_rows_bf16<<<dim3(2 * size), dim3(256), 0, stream>>>(
        WA, WB, pA, pB, size, prev_size);
    table_coef<<<dim3((size + 255) / 256), dim3(256), 0, stream>>>(TW, coef, size);
    transpose_bf16<<<dim3(batch / 64, prev_size / 64), dim3(256), 0, stream>>>(
        prev, prevT, prev_size, batch);
    dual_gemm8<<<dim3(batch / 256, size / 128), dim3(512), 0, stream>>>(
        pA, pB, prevT, coef, out);
}

// Round 3
// 93.454 us; speedup vs baseline: 1.0882x; 1.0212x over previous
//
#include <hip/hip_runtime.h>
#include <hip/hip_bf16.h>

// ---------------------------------------------------------------------------
// LogicLayer inference (size=1024, prev=1024, batch=16384)
//   out[s,n] = w0[s] + wA[s]*a + wB[s]*b + wAB[s]*a*b,  a = pA@prev, b = pB@prev
// Round 3: register-level software pipelining of the dual GEMM.
//   - frag ds_reads issued one MFMA-cluster ahead -> LDS pipe overlaps matrix pipe
//   - counted lgkmcnt(4)/lgkmcnt(8) (DS completes in-order), never 0 in loop
//   - ONE barrier per K-tile (was 4), at the staged-buffer handoff (counted vmcnt)
//   - bf0/bf1 named double-buffered B-frags (no runtime indexing -> no scratch)
//   - sched_barrier(0) after each counted wait (rule #18)
// ---------------------------------------------------------------------------

typedef __attribute__((ext_vector_type(8))) short bf16x8;
typedef __attribute__((ext_vector_type(4))) float f32x4;

__device__ __forceinline__ void gload_lds16(const void* g, void* l) {
    __builtin_amdgcn_global_load_lds(
        (const __attribute__((address_space(1))) void*)g,
        (__attribute__((address_space(3))) void*)l, 16, 0, 0);
}

// ---------------- kernel 1: row softmax of WA/WB -> bf16 -------------------
__global__ __launch_bounds__(256) void softmax_rows_bf16(
    const float* __restrict__ WA, const float* __restrict__ WB,
    __hip_bfloat16* __restrict__ PA, __hip_bfloat16* __restrict__ PB,
    int rows, int cols)
{
    const int b = blockIdx.x;
    const float* W;
    __hip_bfloat16* P;
    if (b < rows) { W = WA + (size_t)b * cols;          P = PA + (size_t)b * cols; }
    else          { W = WB + (size_t)(b - rows) * cols; P = PB + (size_t)(b - rows) * cols; }

    const int t = threadIdx.x;
    const int wave = t >> 6, lane = t & 63;

    float4 v = *(const float4*)&W[t * 4];
    float mx = fmaxf(fmaxf(v.x, v.y), fmaxf(v.z, v.w));
    #pragma unroll
    for (int off = 32; off; off >>= 1) mx = fmaxf(mx, __shfl_xor(mx, off));

    __shared__ float redmax[4];
    __shared__ float redsum[4];
    if (lane == 0) redmax[wave] = mx;
    __syncthreads();
    mx = fmaxf(fmaxf(redmax[0], redmax[1]), fmaxf(redmax[2], redmax[3]));

    float e0 = __expf(v.x - mx), e1 = __expf(v.y - mx);
    float e2 = __expf(v.z - mx), e3 = __expf(v.w - mx);
    float s = e0 + e1 + e2 + e3;
    #pragma unroll
    for (int off = 32; off; off >>= 1) s += __shfl_xor(s, off);
    if (lane == 0) redsum[wave] = s;
    __syncthreads();
    s = redsum[0] + redsum[1] + redsum[2] + redsum[3];

    const float inv = 1.0f / s;
    __align__(8) __hip_bfloat16 o[4];
    o[0] = __float2bfloat16(e0 * inv);
    o[1] = __float2bfloat16(e1 * inv);
    o[2] = __float2bfloat16(e2 * inv);
    o[3] = __float2bfloat16(e3 * inv);
    *(uint2*)&P[t * 4] = *(const uint2*)o;
}

// ---------------- kernel 2: table softmax -> bilinear coeffs ----------------
__global__ void table_coef(const float* __restrict__ TW, float4* __restrict__ coef, int size)
{
    const int s = blockIdx.x * blockDim.x + threadIdx.x;
    if (s >= size) return;
    float p[16];
    float mx = -1e30f;
    #pragma unroll
    for (int g = 0; g < 16; ++g) { p[g] = TW[g * size + s]; mx = fmaxf(mx, p[g]); }
    float sum = 0.f;
    #pragma unroll
    for (int g = 0; g < 16; ++g) { p[g] = __expf(p[g] - mx); sum += p[g]; }
    const float inv = 1.0f / sum;
    #pragma unroll
    for (int g = 0; g < 16; ++g) p[g] *= inv;

    float w0  = p[8] + p[9] + p[10] + p[11] + p[12] + p[13] + p[14] + p[15];
    float wA  = p[2] + p[3] + p[6] + p[7] - p[8] - p[9] - p[12] - p[13];
    float wB  = p[4] + p[5] + p[6] + p[7] - p[8] - p[9] - p[10] - p[11];
    float wAB = p[1] - p[2] - p[4] - 2.f * p[6] - p[7]
              + p[8] + 2.f * p[9] + p[11] + p[13] - p[14];
    coef[s] = make_float4(w0, wA, wB, wAB);
}

// ---------------- kernel 3: prev (K x N f32) -> prevT (N x K bf16) ----------
__global__ __launch_bounds__(256) void transpose_bf16(
    const float* __restrict__ prev, __hip_bfloat16* __restrict__ prevT,
    int K, int N)
{
    __shared__ float ls[64][65];
    const int k0 = blockIdx.y * 64, n0 = blockIdx.x * 64;
    const int t = threadIdx.x;

    {
        const int kr = t >> 4, nc = (t & 15) * 4;
        #pragma unroll
        for (int i = 0; i < 4; ++i) {
            const int k = i * 16 + kr;
            float4 v = *(const float4*)&prev[(size_t)(k0 + k) * N + n0 + nc];
            ls[k][nc + 0] = v.x; ls[k][nc + 1] = v.y;
            ls[k][nc + 2] = v.z; ls[k][nc + 3] = v.w;
        }
    }
    __syncthreads();
    {
        const int n = t >> 2, kc = (t & 3) * 16;
        __align__(16) __hip_bfloat16 tmp[16];
        #pragma unroll
        for (int j = 0; j < 16; ++j) tmp[j] = __float2bfloat16(ls[kc + j][n]);
        __hip_bfloat16* dst = &prevT[(size_t)(n0 + n) * K + k0 + kc];
        *(uint4*)(dst + 0) = *(const uint4*)&tmp[0];
        *(uint4*)(dst + 8) = *(const uint4*)&tmp[8];
    }
}

// ---------------- kernel 4: pipelined dual GEMM -----------------------------
// Block tile: 256 stacked A-rows (128 pA + 128 pB) x 256 cols, BK=32.
// 8 waves in 2(M-half: a/b) x 4(N), each wave 128x64 output (8x4 frags).
// LDS: 4 buffers x 32KB = 128KB, 3-tile prefetch lead, counted vmcnt(8).
constexpr int BK_   = 32;
constexpr int NTIL  = 32;        // 1024 / 32
constexpr int BUF   = 32768;     // bytes per buffer
constexpr int BOFF_ = 16384;     // B offset within buffer
constexpr int Kd    = 1024;
constexpr int Nd    = 16384;

__global__ __launch_bounds__(512, 2) void dual_gemm8(
    const __hip_bfloat16* __restrict__ pA,
    const __hip_bfloat16* __restrict__ pB,
    const __hip_bfloat16* __restrict__ prevT,
    const float4* __restrict__ coef,
    float* __restrict__ out)
{
    __shared__ __align__(16) char smem[131072];

    const int t = threadIdx.x;
    const int wave = t >> 6, lane = t & 63;
    const int wr = wave >> 2, wc = wave & 3;      // wr: 0=a-half, 1=b-half
    const int m0 = blockIdx.y * 128;
    const int n0 = blockIdx.x * 256;

    // --- fragment-read addressing (byte offsets, buffer-relative) ---
    const int fr  = lane & 15;
    const int kg  = lane >> 4;                              // k-chunk 0..3
    const int csw = ((kg ^ ((fr >> 1) & 3)) << 4);          // swizzled chunk
    const int aoff = (wr * 128 + fr) * 64 + csw;            // + i*1024
    const int boff = BOFF_ + (wc * 64 + fr) * 64 + csw;     // + j*1024

    // --- staging addressing (per-lane global src, pre-swizzled k) ---
    const int srow = lane >> 2;
    const int sksw = ((lane & 3) ^ ((lane >> 3) & 3)) * 8;
    const int arow = 16 * wave + srow;
    const __hip_bfloat16* gA0 = pA    + (size_t)(m0 + arow) * Kd + sksw;
    const __hip_bfloat16* gA1 = pB    + (size_t)(m0 + arow) * Kd + sksw;
    const __hip_bfloat16* gB0 = prevT + (size_t)(n0 + arow) * Kd + sksw;
    const __hip_bfloat16* gB1 = prevT + (size_t)(n0 + 128 + arow) * Kd + sksw;

    auto STAGE_A = [&](int T) {
        char* base = smem + (T & 3) * BUF + wave * 1024;
        const int kT = T * BK_;
        gload_lds16(gA0 + kT, base);
        gload_lds16(gA1 + kT, base + 8192);
    };
    auto STAGE_B = [&](int T) {
        char* base = smem + (T & 3) * BUF + BOFF_ + wave * 1024;
        const int kT = T * BK_;
        gload_lds16(gB0 + kT, base);
        gload_lds16(gB1 + kT, base + 8192);
    };

    f32x4 acc[8][4] = {};
    bf16x8 a03[4], a47[4], bf0[4], bf1[4];

// One K-tile, register-pipelined:
//  [issue a47 reads]  lgkmcnt(4)  [MFMA a03 x BCUR  ||  LDS serves a47]
//  [stage tt+3]  vmcnt  BARRIER
//  [issue a03/BNXT reads from buf tt+1]  lgkmcnt(8)
//  [MFMA a47 x BCUR  ||  LDS serves next-tile reads]
#define DO_TILE(TT, STG, VMSTR, BCUR, BNXT)                                 \
  {                                                                         \
    const char* buf  = smem + ((TT) & 3) * BUF;                             \
    const char* nbuf = smem + (((TT) + 1) & 3) * BUF;                       \
    _Pragma("unroll")                                                       \
    for (int i = 0; i < 4; ++i)                                             \
        a47[i] = *(const bf16x8*)(buf + aoff + (4 + i) * 1024);             \
    asm volatile("s_waitcnt lgkmcnt(4)" ::: "memory");                      \
    __builtin_amdgcn_sched_barrier(0);                                      \
    __builtin_amdgcn_s_setprio(1);                                          \
    _Pragma("unroll")                                                       \
    for (int i = 0; i < 4; ++i) {                                           \
      _Pragma("unroll")                                                     \
      for (int j = 0; j < 4; ++j)                                           \
        acc[i][j] = __builtin_amdgcn_mfma_f32_16x16x32_bf16(                \
            a03[i], BCUR[j], acc[i][j], 0, 0, 0);                           \
    }                                                                       \
    __builtin_amdgcn_s_setprio(0);                                          \
    if (STG) { STAGE_A((TT) + 3); STAGE_B((TT) + 3); }                      \
    asm volatile("s_waitcnt " VMSTR ::: "memory");                          \
    __builtin_amdgcn_s_barrier();                                           \
    _Pragma("unroll")                                                       \
    for (int i = 0; i < 4; ++i)                                             \
        a03[i] = *(const bf16x8*)(nbuf + aoff + i * 1024);                  \
    _Pragma("unroll")                                                       \
    for (int j = 0; j < 4; ++j)                                             \
        BNXT[j] = *(const bf16x8*)(nbuf + boff + j * 1024);                 \
    asm volatile("s_waitcnt lgkmcnt(8)" ::: "memory");                      \
    __builtin_amdgcn_sched_barrier(0);                                      \
    __builtin_amdgcn_s_setprio(1);                                          \
    _Pragma("unroll")                                                       \
    for (int i = 0; i < 4; ++i) {                                           \
      _Pragma("unroll")                                                     \
      for (int j = 0; j < 4; ++j)                                           \
        acc[4 + i][j] = __builtin_amdgcn_mfma_f32_16x16x32_bf16(            \
            a47[i], BCUR[j], acc[4 + i][j], 0, 0, 0);                       \
    }                                                                       \
    __builtin_amdgcn_s_setprio(0);                                          \
  }

// last tile: no staging, no barrier, drain lgkm fully
#define DO_LAST(BCUR)                                                       \
  {                                                                         \
    const char* buf = smem + ((NTIL - 1) & 3) * BUF;                        \
    _Pragma("unroll")                                                       \
    for (int i = 0; i < 4; ++i)                                             \
        a47[i] = *(const bf16x8*)(buf + aoff + (4 + i) * 1024);             \
    asm volatile("s_waitcnt lgkmcnt(4)" ::: "memory");                      \
    __builtin_amdgcn_sched_barrier(0);                                      \
    __builtin_amdgcn_s_setprio(1);                                          \
    _Pragma("unroll")                                                       \
    for (int i = 0; i < 4; ++i) {                                           \
      _Pragma("unroll")                                                     \
      for (int j = 0; j < 4; ++j)                                           \
        acc[i][j] = __builtin_amdgcn_mfma_f32_16x16x32_bf16(                \
            a03[i], BCUR[j], acc[i][j], 0, 0, 0);                           \
    }                                                                       \
    asm volatile("s_waitcnt lgkmcnt(0)" ::: "memory");                      \
    __builtin_amdgcn_sched_barrier(0);                                      \
    _Pragma("unroll")                                                       \
    for (int i = 0; i < 4; ++i) {                                           \
      _Pragma("unroll")                                                     \
      for (int j = 0; j < 4; ++j)                                           \
        acc[4 + i][j] = __builtin_amdgcn_mfma_f32_16x16x32_bf16(            \
            a47[i], BCUR[j], acc[4 + i][j], 0, 0, 0);                       \
    }                                                                       \
    __builtin_amdgcn_s_setprio(0);                                          \
  }

    // prologue: stage tiles 0..2, wait buf0, preload tile-0 frags
    STAGE_A(0); STAGE_B(0);
    STAGE_A(1); STAGE_B(1);
    STAGE_A(2); STAGE_B(2);
    asm volatile("s_waitcnt vmcnt(8)" ::: "memory");
    __builtin_amdgcn_s_barrier();
    #pragma unroll
    for (int i = 0; i < 4; ++i)
        a03[i] = *(const bf16x8*)(smem + aoff + i * 1024);
    #pragma unroll
    for (int j = 0; j < 4; ++j)
        bf0[j] = *(const bf16x8*)(smem + boff + j * 1024);

    // steady: tiles 0..27 (stage up to tile 30)
    for (int tt = 0; tt < 28; tt += 2) {
        DO_TILE(tt,     1, "vmcnt(8)", bf0, bf1)
        DO_TILE(tt + 1, 1, "vmcnt(8)", bf1, bf0)
    }
    DO_TILE(28, 1, "vmcnt(8)", bf0, bf1)   // stages tile 31
    DO_TILE(29, 0, "vmcnt(4)", bf1, bf0)
    DO_TILE(30, 0, "vmcnt(0)", bf0, bf1)
    DO_LAST(bf1)

#undef DO_TILE
#undef DO_LAST

    // ---- epilogue: exchange b-acc via LDS, fuse bilinear coefficients ----
    __syncthreads();
    if (wr == 1) {
        #pragma unroll
        for (int i = 0; i < 8; ++i) {
            #pragma unroll
            for (int j = 0; j < 4; ++j) {
                const int off = ((((wc * 8 + i) * 4 + j) * 64) + lane) * 16;
                *(f32x4*)(smem + off) = acc[i][j];
            }
        }
    }
    __syncthreads();
    if (wr == 0) {
        const int hi = lane >> 4;
        #pragma unroll
        for (int i = 0; i < 8; ++i) {
            float4 cc[4];
            #pragma unroll
            for (int r = 0; r < 4; ++r) cc[r] = coef[m0 + i * 16 + hi * 4 + r];
            #pragma unroll
            for (int j = 0; j < 4; ++j) {
                const f32x4 bb = *(const f32x4*)(smem + ((((wc * 8 + i) * 4 + j) * 64) + lane) * 16);
                const int n = n0 + wc * 64 + j * 16 + fr;
                #pragma unroll
                for (int r = 0; r < 4; ++r) {
                    const int m = m0 + i * 16 + hi * 4 + r;
                    const float a = acc[i][j][r];
                    out[(size_t)m * Nd + n] = cc[r].x + cc[r].y * a + cc[r].z * bb[r]
                                            + cc[r].w * (a * bb[r]);
                }
            }
        }
    }
}

// ---------------------------------------------------------------------------
extern "C" void kernel_launch(void* const* d_in, const int* in_sizes, int n_in,
                              void* d_out, int out_size, void* d_ws, size_t ws_size,
                              hipStream_t stream)
{
    const float* prev = (const float*)d_in[0];   // (prev_size, batch)
    const float* WA   = (const float*)d_in[1];   // (size, prev_size)
    const float* WB   = (const float*)d_in[2];   // (size, prev_size)
    const float* TW   = (const float*)d_in[3];   // (16, size)
    float* out = (float*)d_out;                  // (size, batch)

    const int size      = in_sizes[3] / 16;          // 1024
    const int prev_size = in_sizes[1] / size;        // 1024
    const int batch     = in_sizes[0] / prev_size;   // 16384

    char* ws = (char*)d_ws;
    __hip_bfloat16* prevT = (__hip_bfloat16*)ws;     // 32MB
    size_t off = (size_t)batch * prev_size * sizeof(__hip_bfloat16);
    __hip_bfloat16* pA = (__hip_bfloat16*)(ws + off);
    off += (size_t)size * prev_size * sizeof(__hip_bfloat16);
    __hip_bfloat16* pB = (__hip_bfloat16*)(ws + off);
    off += (size_t)size * prev_size * sizeof(__hip_bfloat16);
    float4* coef = (float4*)(ws + off);

    softmax_rows_bf16<<<dim3(2 * size), dim3(256), 0, stream>>>(
        WA, WB, pA, pB, size, prev_size);
    table_coef<<<dim3((size + 255) / 256), dim3(256), 0, stream>>>(TW, coef, size);
    transpose_bf16<<<dim3(batch / 64, prev_size / 64), dim3(256), 0, stream>>>(
        prev, prevT, prev_size, batch);
    dual_gemm8<<<dim3(batch / 256, size / 128), dim3(512), 0, stream>>>(
        pA, pB, prevT, coef, out);
}

// Round 4
// 91.289 us; speedup vs baseline: 1.1141x; 1.0237x over previous
//
#include <hip/hip_runtime.h>
#include <hip/hip_bf16.h>

// ---------------------------------------------------------------------------
// LogicLayer inference (size=1024, prev=1024, batch=16384)
//   out[s,n] = w0[s] + wA[s]*a + wB[s]*b + wAB[s]*a*b,  a = pA@prev, b = pB@prev
// Round 4: m201 8-phase template port (measured 1563 TF on plain 256^2 GEMM).
//   - BK=64, 2 LDS buffers x 64KB, 4 half-tiles/buffer (A-pA, A-pB, B-lo, B-hi)
//   - 4 phases per K-tile: {ds_reads, stage 1 half-tile, vmcnt(6), barrier,
//       lgkmcnt(0)+sched_barrier, setprio(1)+16 MFMA+setprio(0), barrier}
//   - stage stream 3 half-tiles in flight; vmcnt never drains to 0 mid-loop
//   - chunk-XOR swizzle (8 chunks/128B row), pre-swizzled global source
// ---------------------------------------------------------------------------

typedef __attribute__((ext_vector_type(8))) short bf16x8;
typedef __attribute__((ext_vector_type(4))) float f32x4;

__device__ __forceinline__ void gload_lds16(const void* g, void* l) {
    __builtin_amdgcn_global_load_lds(
        (const __attribute__((address_space(1))) void*)g,
        (__attribute__((address_space(3))) void*)l, 16, 0, 0);
}

// ---------------- kernel 1: row softmax of WA/WB -> bf16 -------------------
__global__ __launch_bounds__(256) void softmax_rows_bf16(
    const float* __restrict__ WA, const float* __restrict__ WB,
    __hip_bfloat16* __restrict__ PA, __hip_bfloat16* __restrict__ PB,
    int rows, int cols)
{
    const int b = blockIdx.x;
    const float* W;
    __hip_bfloat16* P;
    if (b < rows) { W = WA + (size_t)b * cols;          P = PA + (size_t)b * cols; }
    else          { W = WB + (size_t)(b - rows) * cols; P = PB + (size_t)(b - rows) * cols; }

    const int t = threadIdx.x;
    const int wave = t >> 6, lane = t & 63;

    float4 v = *(const float4*)&W[t * 4];
    float mx = fmaxf(fmaxf(v.x, v.y), fmaxf(v.z, v.w));
    #pragma unroll
    for (int off = 32; off; off >>= 1) mx = fmaxf(mx, __shfl_xor(mx, off));

    __shared__ float redmax[4];
    __shared__ float redsum[4];
    if (lane == 0) redmax[wave] = mx;
    __syncthreads();
    mx = fmaxf(fmaxf(redmax[0], redmax[1]), fmaxf(redmax[2], redmax[3]));

    float e0 = __expf(v.x - mx), e1 = __expf(v.y - mx);
    float e2 = __expf(v.z - mx), e3 = __expf(v.w - mx);
    float s = e0 + e1 + e2 + e3;
    #pragma unroll
    for (int off = 32; off; off >>= 1) s += __shfl_xor(s, off);
    if (lane == 0) redsum[wave] = s;
    __syncthreads();
    s = redsum[0] + redsum[1] + redsum[2] + redsum[3];

    const float inv = 1.0f / s;
    __align__(8) __hip_bfloat16 o[4];
    o[0] = __float2bfloat16(e0 * inv);
    o[1] = __float2bfloat16(e1 * inv);
    o[2] = __float2bfloat16(e2 * inv);
    o[3] = __float2bfloat16(e3 * inv);
    *(uint2*)&P[t * 4] = *(const uint2*)o;
}

// ---------------- kernel 2: table softmax -> bilinear coeffs ----------------
__global__ void table_coef(const float* __restrict__ TW, float4* __restrict__ coef, int size)
{
    const int s = blockIdx.x * blockDim.x + threadIdx.x;
    if (s >= size) return;
    float p[16];
    float mx = -1e30f;
    #pragma unroll
    for (int g = 0; g < 16; ++g) { p[g] = TW[g * size + s]; mx = fmaxf(mx, p[g]); }
    float sum = 0.f;
    #pragma unroll
    for (int g = 0; g < 16; ++g) { p[g] = __expf(p[g] - mx); sum += p[g]; }
    const float inv = 1.0f / sum;
    #pragma unroll
    for (int g = 0; g < 16; ++g) p[g] *= inv;

    float w0  = p[8] + p[9] + p[10] + p[11] + p[12] + p[13] + p[14] + p[15];
    float wA  = p[2] + p[3] + p[6] + p[7] - p[8] - p[9] - p[12] - p[13];
    float wB  = p[4] + p[5] + p[6] + p[7] - p[8] - p[9] - p[10] - p[11];
    float wAB = p[1] - p[2] - p[4] - 2.f * p[6] - p[7]
              + p[8] + 2.f * p[9] + p[11] + p[13] - p[14];
    coef[s] = make_float4(w0, wA, wB, wAB);
}

// ---------------- kernel 3: prev (K x N f32) -> prevT (N x K bf16) ----------
__global__ __launch_bounds__(256) void transpose_bf16(
    const float* __restrict__ prev, __hip_bfloat16* __restrict__ prevT,
    int K, int N)
{
    __shared__ float ls[64][65];
    const int k0 = blockIdx.y * 64, n0 = blockIdx.x * 64;
    const int t = threadIdx.x;

    {
        const int kr = t >> 4, nc = (t & 15) * 4;
        #pragma unroll
        for (int i = 0; i < 4; ++i) {
            const int k = i * 16 + kr;
            float4 v = *(const float4*)&prev[(size_t)(k0 + k) * N + n0 + nc];
            ls[k][nc + 0] = v.x; ls[k][nc + 1] = v.y;
            ls[k][nc + 2] = v.z; ls[k][nc + 3] = v.w;
        }
    }
    __syncthreads();
    {
        const int n = t >> 2, kc = (t & 3) * 16;
        __align__(16) __hip_bfloat16 tmp[16];
        #pragma unroll
        for (int j = 0; j < 16; ++j) tmp[j] = __float2bfloat16(ls[kc + j][n]);
        __hip_bfloat16* dst = &prevT[(size_t)(n0 + n) * K + k0 + kc];
        *(uint4*)(dst + 0) = *(const uint4*)&tmp[0];
        *(uint4*)(dst + 8) = *(const uint4*)&tmp[8];
    }
}

// ---------------- kernel 4: 8-phase dual GEMM (m201 skeleton) ---------------
// Block: 256 stacked A-rows (128 pA + 128 pB) x 256 cols, BK=64, 16 K-tiles.
// 8 waves 2(panel)x4(N), per-wave 128x64 out = 8x4 16x16 frags.
// LDS buffer (64KB): [A-pA 16K][A-pB 16K][B-lo 16K][B-hi 16K]; 2 buffers.
// Rows are 128B (64 bf16); chunk c in 0..7; LDS[r][c] = G[r][c ^ (r&7)].
constexpr int Kd = 1024;
constexpr int Nd = 16384;

__global__ __launch_bounds__(512, 2) void dual_gemm8(
    const __hip_bfloat16* __restrict__ pA,
    const __hip_bfloat16* __restrict__ pB,
    const __hip_bfloat16* __restrict__ prevT,
    const float4* __restrict__ coef,
    float* __restrict__ out)
{
    __shared__ __align__(16) char smem[131072];

    const int t_ = threadIdx.x;
    const int wave = t_ >> 6, lane = t_ & 63;
    const int wr = wave >> 2, wc = wave & 3;      // wr: 0=pA panel, 1=pB panel
    const int m0 = blockIdx.y * 128;
    const int n0 = blockIdx.x * 256;

    // fragment-read addressing
    const int fr  = lane & 15;
    const int kg  = lane >> 4;                    // 16B chunk within 32-k step
    const int fsw = fr & 7;
    const int c0 = (kg ^ fsw) * 16;               // kstep 0 chunk byte
    const int c1 = ((4 + kg) ^ fsw) * 16;         // kstep 1 chunk byte
    const int aoffs = (wr * 128 + fr) * 128;      // + i*2048 (+8192 for hi)
    const int boffs = 32768 + (wc * 64 + fr) * 128;  // + j*2048

    // staging addressing (pre-swizzled global source)
    const int sr  = lane >> 3;                    // row within 8-row group
    const int swz = ((lane & 7) ^ sr) * 8;        // swizzled k elems
    const int r0  = wave * 16 + sr;               // rows for q=0 (q=1: +8)
    const __hip_bfloat16* gA0 = pA    + (size_t)(m0 + r0) * Kd + swz;
    const __hip_bfloat16* gA1 = pB    + (size_t)(m0 + r0) * Kd + swz;
    const __hip_bfloat16* gB0 = prevT + (size_t)(n0 + r0) * Kd + swz;
    const __hip_bfloat16* gB1 = prevT + (size_t)(n0 + 128 + r0) * Kd + swz;

    f32x4 acc[8][4] = {};
    bf16x8 a[8], b[8];

#define STG(GP, BB, HOFF, KT) {                                             \
    char* lb = smem + (BB) + (HOFF) + wave * 2048;                          \
    gload_lds16((GP) + (KT), lb);                                           \
    gload_lds16((GP) + (KT) + 8 * Kd, lb + 1024); }

#define RD_ALO(BB) _Pragma("unroll") for (int i = 0; i < 4; ++i) {          \
    a[i*2]   = *(const bf16x8*)(smem + (BB) + aoffs + i * 2048 + c0);       \
    a[i*2+1] = *(const bf16x8*)(smem + (BB) + aoffs + i * 2048 + c1); }
#define RD_AHI(BB) _Pragma("unroll") for (int i = 0; i < 4; ++i) {          \
    a[i*2]   = *(const bf16x8*)(smem + (BB) + aoffs + 8192 + i * 2048 + c0);\
    a[i*2+1] = *(const bf16x8*)(smem + (BB) + aoffs + 8192 + i * 2048 + c1); }
#define RD_BLO(BB) _Pragma("unroll") for (int j = 0; j < 2; ++j) {          \
    b[j*2]   = *(const bf16x8*)(smem + (BB) + boffs + j * 2048 + c0);       \
    b[j*2+1] = *(const bf16x8*)(smem + (BB) + boffs + j * 2048 + c1); }
#define RD_BHI(BB) _Pragma("unroll") for (int j = 0; j < 2; ++j) {          \
    b[4+j*2]   = *(const bf16x8*)(smem + (BB) + boffs + 4096 + j * 2048 + c0); \
    b[4+j*2+1] = *(const bf16x8*)(smem + (BB) + boffs + 4096 + j * 2048 + c1); }

#define BAR __builtin_amdgcn_s_barrier()
#define VMW(S) asm volatile("s_waitcnt " S ::: "memory")

#define MM(I0, J0, BB0)                                                     \
    asm volatile("s_waitcnt lgkmcnt(0)" ::: "memory");                      \
    __builtin_amdgcn_sched_barrier(0);                                      \
    __builtin_amdgcn_s_setprio(1);                                          \
    _Pragma("unroll") for (int i = 0; i < 4; ++i)                           \
    _Pragma("unroll") for (int j = 0; j < 2; ++j)                           \
    _Pragma("unroll") for (int ks = 0; ks < 2; ++ks)                        \
        acc[(I0)+i][(J0)+j] = __builtin_amdgcn_mfma_f32_16x16x32_bf16(      \
            a[i*2+ks], b[(BB0)+j*2+ks], acc[(I0)+i][(J0)+j], 0, 0, 0);      \
    __builtin_amdgcn_s_setprio(0);

// One K-tile = 4 phases. Stage map (verified by per-wave vmcnt simulation):
//  ph1: A-pA(T+1)->NXT   ph2: A-pB(T+1)->NXT   ph3: B-lo(T+2)->CUR   ph4: B-hi(T+2)->CUR
// WAR: B(T+2) into CUR only after ph2's trailing barrier (all B reads done);
//      A(T+1) into NXT (dead since tile T-1 ended). vmcnt(6) = 3 half-tiles.
#define TILE(T, CURB, NXTB, SA, SB, VM1) {                                  \
    RD_ALO(CURB) RD_BLO(CURB)                                               \
    if (SA) STG(gA0, NXTB, 0, ((T)+1)*64)                                   \
    asm volatile("s_waitcnt lgkmcnt(8)" ::: "memory");                      \
    VMW(VM1); BAR;                                                          \
    MM(0, 0, 0) BAR;                                                        \
    RD_BHI(CURB)                                                            \
    if (SA) STG(gA1, NXTB, 16384, ((T)+1)*64)                               \
    VMW("vmcnt(6)"); BAR;                                                   \
    MM(0, 2, 4) BAR;                                                        \
    RD_AHI(CURB)                                                            \
    if (SB) STG(gB0, CURB, 32768, ((T)+2)*64)                               \
    VMW("vmcnt(6)"); BAR;                                                   \
    MM(4, 2, 4) BAR;                                                        \
    if (SB) STG(gB1, CURB, 49152, ((T)+2)*64)                               \
    VMW("vmcnt(6)"); BAR;                                                   \
    MM(4, 0, 0) BAR;                                                        \
}

    // prologue: tile0 all 4 halves -> buf0; tile1 B-halves -> buf1.
    STG(gB0, 0, 32768, 0)
    STG(gB1, 0, 49152, 0)
    STG(gA0, 0, 0,     0)
    STG(gA1, 0, 16384, 0)
    STG(gB0, 65536, 32768, 64)
    STG(gB1, 65536, 49152, 64)
    VMW("vmcnt(4)");         // confirm tile0's 8 loads; 2 halves in flight
    BAR;

    for (int t = 0; t < 14; t += 2) {
        TILE(t,     0,     65536, 1, 1, "vmcnt(6)")
        TILE(t + 1, 65536, 0,     1, 1, "vmcnt(6)")
    }
    TILE(14, 0,     65536, 1, 0, "vmcnt(6)")
    TILE(15, 65536, 0,     0, 0, "vmcnt(0)")

#undef TILE
#undef MM
#undef STG
#undef RD_ALO
#undef RD_AHI
#undef RD_BLO
#undef RD_BHI
#undef BAR
#undef VMW

    // ---- epilogue: exchange b-acc via LDS, fuse bilinear coefficients ----
    __syncthreads();
    if (wr == 1) {
        #pragma unroll
        for (int i = 0; i < 8; ++i) {
            #pragma unroll
            for (int j = 0; j < 4; ++j) {
                const int off = ((((wc * 8 + i) * 4 + j) * 64) + lane) * 16;
                *(f32x4*)(smem + off) = acc[i][j];
            }
        }
    }
    __syncthreads();
    if (wr == 0) {
        const int hi = lane >> 4;
        #pragma unroll
        for (int i = 0; i < 8; ++i) {
            float4 cc[4];
            #pragma unroll
            for (int r = 0; r < 4; ++r) cc[r] = coef[m0 + i * 16 + hi * 4 + r];
            #pragma unroll
            for (int j = 0; j < 4; ++j) {
                const f32x4 bb = *(const f32x4*)(smem + ((((wc * 8 + i) * 4 + j) * 64) + lane) * 16);
                const int n = n0 + wc * 64 + j * 16 + fr;
                #pragma unroll
                for (int r = 0; r < 4; ++r) {
                    const int m = m0 + i * 16 + hi * 4 + r;
                    const float aa = acc[i][j][r];
                    out[(size_t)m * Nd + n] = cc[r].x + cc[r].y * aa + cc[r].z * bb[r]
                                            + cc[r].w * (aa * bb[r]);
                }
            }
        }
    }
}

// ---------------------------------------------------------------------------
extern "C" void kernel_launch(void* const* d_in, const int* in_sizes, int n_in,
                              void* d_out, int out_size, void* d_ws, size_t ws_size,
                              hipStream_t stream)
{
    const float* prev = (const float*)d_in[0];   // (prev_size, batch)
    const float* WA   = (const float*)d_in[1];   // (size, prev_size)
    const float* WB   = (const float*)d_in[2];   // (size, prev_size)
    const float* TW   = (const float*)d_in[3];   // (16, size)
    float* out = (float*)d_out;                  // (size, batch)

    const int size      = in_sizes[3] / 16;          // 1024
    const int prev_size = in_sizes[1] / size;        // 1024
    const int batch     = in_sizes[0] / prev_size;   // 16384

    char* ws = (char*)d_ws;
    __hip_bfloat16* prevT = (__hip_bfloat16*)ws;     // 32MB
    size_t off = (size_t)batch * prev_size * sizeof(__hip_bfloat16);
    __hip_bfloat16* pA = (__hip_bfloat16*)(ws + off);
    off += (size_t)size * prev_size * sizeof(__hip_bfloat16);
    __hip_bfloat16* pB = (__hip_bfloat16*)(ws + off);
    off += (size_t)size * prev_size * sizeof(__hip_bfloat16);
    float4* coef = (float4*)(ws + off);

    softmax_rows_bf16<<<dim3(2 * size), dim3(256), 0, stream>>>(
        WA, WB, pA, pB, size, prev_size);
    table_coef<<<dim3((size + 255) / 256), dim3(256), 0, stream>>>(TW, coef, size);
    transpose_bf16<<<dim3(batch / 64, prev_size / 64), dim3(256), 0, stream>>>(
        prev, prevT, prev_size, batch);
    dual_gemm8<<<dim3(batch / 256, size / 128), dim3(512), 0, stream>>>(
        pA, pB, prevT, coef, out);
}